// Round 2
// baseline (921.420 us; speedup 1.0000x reference)
//
#include <hip/hip_runtime.h>

typedef __attribute__((ext_vector_type(8))) short short8;
typedef __attribute__((ext_vector_type(4))) float f32x4;

#define S_LEN 2048
#define BATCH 4
#define DM 1024
#define DI 2048
#define DS 64
#define DTR 64
#define XPW 192   // dt_rank + 2*d_state

__device__ __forceinline__ unsigned short f2bf(float f){
  unsigned u = __builtin_bit_cast(unsigned, f);
  u += 0x7fffu + ((u >> 16) & 1u);
  return (unsigned short)(u >> 16);
}
__device__ __forceinline__ float bf2f(unsigned short h){
  unsigned u = ((unsigned)h) << 16;
  return __builtin_bit_cast(float, u);
}
__device__ __forceinline__ float rdl(float v, int l){
  return __builtin_bit_cast(float, __builtin_amdgcn_readlane(__builtin_bit_cast(int, v), l));
}
__device__ __forceinline__ void gload16(const void* g, void* l){
  __builtin_amdgcn_global_load_lds((const __attribute__((address_space(1))) void*)g,
                                   (__attribute__((address_space(3))) void*)l, 16, 0, 0);
}
__device__ __forceinline__ float siluf_(float v){ return v / (1.f + __expf(-v)); }

// ---------------- f32 -> bf16 convert ----------------
__global__ __launch_bounds__(256) void cvt_bf16_k(const float* __restrict__ in,
                                                  unsigned short* __restrict__ out, int n){
  int i = (blockIdx.x * 256 + threadIdx.x) * 4;
  if (i >= n) return;
  float4 v = *(const float4*)(in + i);
  ushort4 o;
  o.x = f2bf(v.x); o.y = f2bf(v.y); o.z = f2bf(v.z); o.w = f2bf(v.w);
  *(ushort4*)(out + i) = o;
}

// ---------------- bf16 MFMA GEMM, C = A[M,K] * B[N,K]^T + bias ----------------
// 128x128 tile, BK=32, 4 waves (2x2), 16x16x32 MFMA, global_load_lds width=16.
// EPI 0: row-major C=v+bias (f32) and optional bf16 dup Cb.
// EPI 1: dt mode: softplus(v+2*bias) -> transposed T1[b][d][t] f32 only.
// EPI 2: in-proj: col<nsilu -> row-major C (f32); col>=nsilu -> silu -> transposed bf16 T2.
template<int EPI, bool WB16>
__global__ __launch_bounds__(256)
void gemm_bt(const unsigned short* __restrict__ A, const unsigned short* __restrict__ B,
             float* __restrict__ C, unsigned short* __restrict__ Cb,
             float* __restrict__ T1, unsigned short* __restrict__ T2,
             const float* __restrict__ bias,
             int N, int K, int lda, int ldb, int ldc, int nsilu)
{
  __shared__ unsigned short As[128 * 32];
  __shared__ unsigned short Bs[128 * 32];
  const int tid  = threadIdx.x;
  const int lane = tid & 63;
  const int wid  = tid >> 6;
  const int bm = blockIdx.x, bn = blockIdx.y;
  const int r0 = tid >> 2;           // 0..63
  const int c0 = (tid & 3) * 8;      // 0,8,16,24
  int brow0 = bn * 128 + r0;        if (brow0 > N - 1) brow0 = N - 1;
  int brow1 = bn * 128 + 64 + r0;   if (brow1 > N - 1) brow1 = N - 1;
  const unsigned short* pa0 = A + (size_t)(bm * 128 + r0) * lda + c0;
  const unsigned short* pa1 = A + (size_t)(bm * 128 + 64 + r0) * lda + c0;
  const unsigned short* pb0 = B + (size_t)brow0 * ldb + c0;
  const unsigned short* pb1 = B + (size_t)brow1 * ldb + c0;
  f32x4 acc[4][4] = {};
  const int fr = lane & 15, fq = lane >> 4;
  const int wm = (wid >> 1) * 64, wn = (wid & 1) * 64;
  const int aoff0 = (wm + fr) * 32 + fq * 8;
  const int boff0 = (wn + fr) * 32 + fq * 8;
  for (int k0 = 0; k0 < K; k0 += 32) {
    __syncthreads();                       // prev-iter LDS reads done
    gload16(pa0 + k0, &As[tid * 8]);
    gload16(pa1 + k0, &As[2048 + tid * 8]);
    gload16(pb0 + k0, &Bs[tid * 8]);
    gload16(pb1 + k0, &Bs[2048 + tid * 8]);
    __syncthreads();                       // drains vmcnt(0): LDS ready
    short8 av[4], bv[4];
#pragma unroll
    for (int i = 0; i < 4; i++) av[i] = *(const short8*)&As[aoff0 + i * 16 * 32];
#pragma unroll
    for (int i = 0; i < 4; i++) bv[i] = *(const short8*)&Bs[boff0 + i * 16 * 32];
#pragma unroll
    for (int i = 0; i < 4; i++)
#pragma unroll
      for (int j = 0; j < 4; j++)
        acc[i][j] = __builtin_amdgcn_mfma_f32_16x16x32_bf16(av[i], bv[j], acc[i][j], 0, 0, 0);
  }
#pragma unroll
  for (int i = 0; i < 4; i++) {
#pragma unroll
    for (int j = 0; j < 4; j++) {
      int gc = bn * 128 + wn + j * 16 + fr;
      if (gc >= N) continue;
      float bb = bias[gc];
#pragma unroll
      for (int e = 0; e < 4; e++) {
        int gr = bm * 128 + wm + i * 16 + fq * 4 + e;
        float v = acc[i][j][e];
        if (EPI == 0) {
          v += bb;
          C[(size_t)gr * ldc + gc] = v;
          if (WB16) Cb[(size_t)gr * ldc + gc] = f2bf(v);
        } else if (EPI == 1) {
          // dt = softplus(v + 2*b_dt), stored transposed [b][d][t]
          v += 2.f * bb;
          v = fmaxf(v, 0.f) + log1pf(__expf(-fabsf(v)));
          T1[((size_t)((gr & 3) * DI + gc)) * S_LEN + (gr >> 2)] = v;
        } else {
          v += bb;
          if (gc < nsilu) {
            C[(size_t)gr * ldc + gc] = v;                   // x_inner row-major
          } else {
            // gate = silu(z), stored transposed bf16 [b][d][t]
            T2[((size_t)((gr & 3) * DI + (gc - nsilu))) * S_LEN + (gr >> 2)] = f2bf(siluf_(v));
          }
        }
      }
    }
  }
}

// ---------------- causal depthwise conv (K=4) + silu, bf16 out ----------------
__global__ __launch_bounds__(256) void conv_k(const float* __restrict__ xi,   // [8192][2048]
                                              const float* __restrict__ cw,
                                              const float* __restrict__ cb,
                                              unsigned short* __restrict__ xconvb)
{
  int idx = blockIdx.x * 256 + threadIdx.x;   // over 8192*2048
  int d = idx & (DI - 1);
  int r = idx >> 11;                           // r = t*B + b
  const float* p = xi + (size_t)r * DI + d;
  float s = cb[d];
  float w0 = cw[d * 4], w1 = cw[d * 4 + 1], w2 = cw[d * 4 + 2], w3 = cw[d * 4 + 3];
  s += w3 * p[0];
  if (r >= 4)  s += w2 * p[-4  * DI];
  if (r >= 8)  s += w1 * p[-8  * DI];
  if (r >= 12) s += w0 * p[-12 * DI];
  s = siluf_(s);
  xconvb[idx] = f2bf(s);
}

// ---------------- transpose x_conv [r][d] -> [b][d][t] (bf16) ----------------
__global__ __launch_bounds__(256) void trans_k(const unsigned short* __restrict__ in,
                                               unsigned short* __restrict__ out)
{
  __shared__ unsigned short tl[64][65];
  int bb = blockIdx.z;
  int t0 = blockIdx.x * 64;
  int d0 = blockIdx.y * 64;
  int tid = threadIdx.x;
#pragma unroll
  for (int p = 0; p < 16; ++p) {
    int idx = tid + p * 256;
    int td = idx & 63, tt = idx >> 6;
    tl[tt][td] = in[(size_t)((t0 + tt) * 4 + bb) * DI + d0 + td];
  }
  __syncthreads();
#pragma unroll
  for (int p = 0; p < 16; ++p) {
    int idx = tid + p * 256;
    int tw = idx & 63, dw = idx >> 6;
    out[((size_t)(bb * DI) + d0 + dw) * S_LEN + t0 + tw] = tl[tw][dw];
  }
}

// ---------------- selective scan: one wave per (b, 4 d-channels), lane = n ----
__global__ __launch_bounds__(256) void scan_k(const float* __restrict__ dtT,
                                              const unsigned short* __restrict__ xT,
                                              const unsigned short* __restrict__ gT,
                                              const float* __restrict__ xp,     // [8192][192]
                                              const float* __restrict__ A_log,
                                              const float* __restrict__ Dv,
                                              const float* __restrict__ state_in,
                                              float* __restrict__ accbuf,
                                              float* __restrict__ state_out)
{
  const int tid  = threadIdx.x;
  const int lane = tid & 63;
  const int gw = blockIdx.x * 4 + (tid >> 6);  // 0..2047
  const int b  = gw >> 9;
  const int d0 = (gw & 511) * 4;
  const float LOG2E = 1.4426950408889634f;
  float a2[4], st[4], acc[4] = {0.f,0.f,0.f,0.f}, sx[4] = {0.f,0.f,0.f,0.f};
#pragma unroll
  for (int j = 0; j < 4; ++j) {
    a2[j] = -__expf(A_log[(size_t)(d0 + j) * DS + lane]) * LOG2E;   // A*log2(e)
    st[j] = state_in[((size_t)(b * DI + d0 + j)) * DS + lane];
  }
  const size_t rowbase = ((size_t)(b * DI + d0)) * S_LEN;
  const float* pdt = dtT + rowbase;
  const unsigned short* px = xT + rowbase;
  const unsigned short* pg = gT + rowbase;
  float cdt[4], cx[4], cg[4];
#pragma unroll
  for (int j = 0; j < 4; ++j) {
    cdt[j] = pdt[j * S_LEN + lane];
    cx[j]  = bf2f(px[j * S_LEN + lane]);
    cg[j]  = bf2f(pg[j * S_LEN + lane]);
  }
  for (int c = 0; c < 32; ++c) {
    // prefetch next chunk (c==31 overreads into adjacent ws scratch; discarded)
    float ndt[4], nx[4], ng[4];
    const int tn = (c + 1) * 64 + lane;
#pragma unroll
    for (int j = 0; j < 4; ++j) {
      ndt[j] = pdt[j * S_LEN + tn];
      nx[j]  = bf2f(px[j * S_LEN + tn]);
      ng[j]  = bf2f(pg[j * S_LEN + tn]);
    }
    float dtc[4], dxc[4], ggc[4];
#pragma unroll
    for (int j = 0; j < 4; ++j) {
      dtc[j] = cdt[j];
      dxc[j] = cdt[j] * cx[j];
      ggc[j] = cg[j];
      sx[j]  = fmaf(cx[j], cg[j], sx[j]);     // D-term partial, per-lane (lane = t within chunk)
    }
    const float* pb = xp + ((size_t)(c * 64) * 4 + b) * XPW + DTR;
#pragma unroll
    for (int s = 0; s < 64; ++s) {
      float Bv = pb[lane];
      float Cv = pb[DS + lane];
      pb += 4 * XPW;
#pragma unroll
      for (int j = 0; j < 4; ++j) {
        float dts = rdl(dtc[j], s);
        float dxs = rdl(dxc[j], s);
        float gs  = rdl(ggc[j], s);
        float dA  = exp2f(dts * a2[j]);
        st[j]  = fmaf(st[j], dA, dxs * Bv);
        acc[j] = fmaf(st[j] * Cv, gs, acc[j]);
      }
    }
#pragma unroll
    for (int j = 0; j < 4; ++j) { cdt[j] = ndt[j]; cx[j] = nx[j]; cg[j] = ng[j]; }
  }
#pragma unroll
  for (int j = 0; j < 4; ++j)
    state_out[((size_t)(b * DI + d0 + j)) * DS + lane] = st[j];
#pragma unroll
  for (int j = 0; j < 4; ++j) {
#pragma unroll
    for (int m = 32; m; m >>= 1) {
      acc[j] += __shfl_xor(acc[j], m, 64);
      sx[j]  += __shfl_xor(sx[j], m, 64);
    }
  }
  if (lane == 0) {
#pragma unroll
    for (int j = 0; j < 4; ++j)
      accbuf[b * DI + d0 + j] = acc[j] + Dv[d0 + j] * sx[j];
  }
}

// ---------------- out = (acc/S) @ W_out^T + b_out ----------------
__global__ __launch_bounds__(256) void out_gemm_k(const float* __restrict__ accb,
                                                  const float* __restrict__ W_out,
                                                  const float* __restrict__ b_out,
                                                  float* __restrict__ outpre)
{
  int b = blockIdx.y;
  int m = blockIdx.x * 8 + (threadIdx.x >> 5);
  int dl = threadIdx.x & 31;
  const float* wr = W_out + (size_t)m * DI;
  const float* ac = accb + b * DI;
  float p = 0.f;
  for (int dd = dl; dd < DI; dd += 32) p = fmaf(wr[dd], ac[dd], p);
#pragma unroll
  for (int s = 16; s; s >>= 1) p += __shfl_xor(p, s, 32);
  if (dl == 0) outpre[b * DM + m] = p * (1.f / 2048.f) + b_out[m];
}

// ---------------- layernorm over d_model ----------------
__global__ __launch_bounds__(256) void ln_k(const float* __restrict__ outpre,
                                            const float* __restrict__ g,
                                            const float* __restrict__ bta,
                                            float* __restrict__ dout)
{
  int b = blockIdx.x;
  const float* row = outpre + b * DM;
  float s = 0.f, s2 = 0.f, vv[4];
#pragma unroll
  for (int i = 0; i < 4; i++) {
    float v = row[threadIdx.x + i * 256];
    vv[i] = v; s += v; s2 += v * v;
  }
#pragma unroll
  for (int m = 32; m; m >>= 1) { s += __shfl_xor(s, m, 64); s2 += __shfl_xor(s2, m, 64); }
  __shared__ float rs[4], rs2[4];
  int w = threadIdx.x >> 6;
  if ((threadIdx.x & 63) == 0) { rs[w] = s; rs2[w] = s2; }
  __syncthreads();
  float S = rs[0] + rs[1] + rs[2] + rs[3];
  float S2 = rs2[0] + rs2[1] + rs2[2] + rs2[3];
  float mu = S * (1.f / 1024.f);
  float var = S2 * (1.f / 1024.f) - mu * mu;
  float inv = rsqrtf(var + 1e-5f);
#pragma unroll
  for (int i = 0; i < 4; i++) {
    int c = threadIdx.x + i * 256;
    dout[b * DM + c] = (vv[i] - mu) * inv * g[c] + bta[c];
  }
}

extern "C" void kernel_launch(void* const* d_in, const int* in_sizes, int n_in,
                              void* d_out, int out_size, void* d_ws, size_t ws_size,
                              hipStream_t stream)
{
  const float* x      = (const float*)d_in[0];
  const float* state0 = (const float*)d_in[1];
  const float* W_in   = (const float*)d_in[2];
  const float* b_in   = (const float*)d_in[3];
  const float* conv_w = (const float*)d_in[4];
  const float* conv_b = (const float*)d_in[5];
  const float* W_xp   = (const float*)d_in[6];
  const float* b_xp   = (const float*)d_in[7];
  const float* W_dt   = (const float*)d_in[8];
  const float* b_dt   = (const float*)d_in[9];
  const float* A_log  = (const float*)d_in[10];
  const float* Dvec   = (const float*)d_in[11];
  const float* W_out  = (const float*)d_in[12];
  const float* b_out  = (const float*)d_in[13];
  const float* ln_g   = (const float*)d_in[14];
  const float* ln_b   = (const float*)d_in[15];
  float* out = (float*)d_out;   // [4*1024] out, then [4*2048*64] final_state

  // ---- workspace layout (byte offsets) ----
  const size_t MB = 1024 * 1024;
  char* ws = (char*)d_ws;
  float*          xz   = (float*)(ws + 0);            // 64MiB [8192][2048] x_inner  [gemm_in -> conv]
  float*          dtT  = (float*)(ws + 0);            // 64MiB [4][2048][2048] f32   [dt-GEMM -> scan] (overlays xz)
  unsigned short* gTb  = (unsigned short*)(ws + 64  * MB); // 32MiB [4][2048][2048] bf16 [gemm_in -> scan]
  unsigned short* xb   = (unsigned short*)(ws + 96  * MB); // 16MiB x bf16          [cvt -> gemm_in]
  unsigned short* wbin = (unsigned short*)(ws + 112 * MB); // 8MiB  W_in bf16       [cvt -> gemm_in]
  unsigned short* xTb  = (unsigned short*)(ws + 96  * MB); // 32MiB x_conv^T bf16   [trans -> scan] (overlays xb+wbin)
  float*          xp   = (float*)(ws + 128 * MB);     // 6MiB  [8192][192] f32
  unsigned short* xpb  = (unsigned short*)(ws + 134 * MB); // 3MiB  xp bf16
  unsigned short* xcb  = (unsigned short*)(ws + 137 * MB); // 32MiB x_conv bf16 [conv -> {xpGEMM, trans}]
  unsigned short* wbxp = (unsigned short*)(ws + 169 * MB); // 768KB
  unsigned short* wbdt = (unsigned short*)(ws + 169 * MB + 786432); // 256KB
  float*          accb   = (float*)(ws + 170 * MB);   // 32KB [4][2048]
  float*          outpre = (float*)(ws + 170 * MB + 32768); // 16KB [4][1024]

  cvt_bf16_k<<<8192, 256, 0, stream>>>(x,    xb,   8388608);
  cvt_bf16_k<<<4096, 256, 0, stream>>>(W_in, wbin, 4194304);
  cvt_bf16_k<<<384,  256, 0, stream>>>(W_xp, wbxp, 393216);
  cvt_bf16_k<<<128,  256, 0, stream>>>(W_dt, wbdt, 131072);
  // xz = x @ W_in^T + b_in; cols<2048 -> x_inner row-major; cols>=2048 -> silu -> gTb transposed
  gemm_bt<2,false><<<dim3(64,32), 256, 0, stream>>>(xb, wbin, xz, nullptr, nullptr, gTb, b_in,
                                                    4096, 1024, 1024, 1024, 2048, 2048);
  conv_k<<<65536, 256, 0, stream>>>(xz, conv_w, conv_b, xcb);
  trans_k<<<dim3(32,32,4), 256, 0, stream>>>(xcb, xTb);
  // xp = x_conv @ W_xp^T + b_xp  (f32 + bf16 dup)
  gemm_bt<0,true><<<dim3(64,2), 256, 0, stream>>>(xcb, wbxp, xp, xpb, nullptr, nullptr, b_xp,
                                                  192, 2048, 2048, 2048, XPW, 0);
  // dtT = softplus(dt_low @ W_dt^T + 2*b_dt) transposed
  gemm_bt<1,false><<<dim3(64,16), 256, 0, stream>>>(xpb, wbdt, nullptr, nullptr, dtT, nullptr, b_dt,
                                                    2048, 64, XPW, 64, 0, 0);
  scan_k<<<512, 256, 0, stream>>>(dtT, xTb, gTb, xp, A_log, Dvec, state0, accb, out + 4096);
  out_gemm_k<<<dim3(128,4), 256, 0, stream>>>(accb, W_out, b_out, outpre);
  ln_k<<<4, 256, 0, stream>>>(outpre, ln_g, ln_b, out);
}

// Round 3
// 693.651 us; speedup vs baseline: 1.3284x; 1.3284x over previous
//
#include <hip/hip_runtime.h>
#include <hip/hip_fp16.h>

typedef __attribute__((ext_vector_type(8))) short short8;
typedef __attribute__((ext_vector_type(4))) float f32x4;

#define S_LEN 2048
#define BATCH 4
#define DM 1024
#define DI 2048
#define DS 64
#define DTR 64
#define XPW 192   // dt_rank + 2*d_state

__device__ __forceinline__ unsigned short f2bf(float f){
  unsigned u = __builtin_bit_cast(unsigned, f);
  u += 0x7fffu + ((u >> 16) & 1u);
  return (unsigned short)(u >> 16);
}
__device__ __forceinline__ float bf2f(unsigned short h){
  unsigned u = ((unsigned)h) << 16;
  return __builtin_bit_cast(float, u);
}
__device__ __forceinline__ void gload16(const void* g, void* l){
  __builtin_amdgcn_global_load_lds((const __attribute__((address_space(1))) void*)g,
                                   (__attribute__((address_space(3))) void*)l, 16, 0, 0);
}
__device__ __forceinline__ float siluf_(float v){ return v / (1.f + __expf(-v)); }

// ---------------- f32 -> bf16 convert ----------------
__global__ __launch_bounds__(256) void cvt_bf16_k(const float* __restrict__ in,
                                                  unsigned short* __restrict__ out, int n){
  int i = (blockIdx.x * 256 + threadIdx.x) * 4;
  if (i >= n) return;
  float4 v = *(const float4*)(in + i);
  ushort4 o;
  o.x = f2bf(v.x); o.y = f2bf(v.y); o.z = f2bf(v.z); o.w = f2bf(v.w);
  *(ushort4*)(out + i) = o;
}

// ---------------- bf16 MFMA GEMM, C = A[M,K] * B[N,K]^T + bias ----------------
// 128x128 tile, BK=32, 4 waves (2x2), 16x16x32 MFMA, global_load_lds width=16.
// EPI 0 (xp):  write Cb=xpb bf16 rm; cols [64,128)->bcI.x, [128,192)->bcI.y (f32).
// EPI 1 (dt):  dt=softplus(v+2*bias); LDS-transpose -> dtTh f16 [b][d][t] and
//              dxgT u32 [b][d][t] = (bf16(dt*x)<<16)|g_bf16 ; x,g read row-major.
// EPI 2 (in):  cols<nsilu -> xib bf16 rm; cols>=nsilu -> g_rm = bf16(silu(v)) rm.
template<int EPI>
__global__ __launch_bounds__(256)
void gemm_bt(const unsigned short* __restrict__ A, const unsigned short* __restrict__ B,
             const float* __restrict__ bias,
             int N, int K, int lda, int ldb,
             void* __restrict__ vp0, void* __restrict__ vp1,
             const void* __restrict__ vp2, const void* __restrict__ vp3, int nsilu)
{
  __shared__ unsigned short As[128 * 32];
  __shared__ unsigned short Bs[128 * 32];
  const int tid  = threadIdx.x;
  const int lane = tid & 63;
  const int wid  = tid >> 6;
  const int bm = blockIdx.x, bn = blockIdx.y;
  const int r0 = tid >> 2;           // 0..63
  const int c0 = (tid & 3) * 8;      // 0,8,16,24
  int brow0 = bn * 128 + r0;        if (brow0 > N - 1) brow0 = N - 1;
  int brow1 = bn * 128 + 64 + r0;   if (brow1 > N - 1) brow1 = N - 1;
  const unsigned short* pa0 = A + (size_t)(bm * 128 + r0) * lda + c0;
  const unsigned short* pa1 = A + (size_t)(bm * 128 + 64 + r0) * lda + c0;
  const unsigned short* pb0 = B + (size_t)brow0 * ldb + c0;
  const unsigned short* pb1 = B + (size_t)brow1 * ldb + c0;
  f32x4 acc[4][4] = {};
  const int fr = lane & 15, fq = lane >> 4;
  const int wm = (wid >> 1) * 64, wn = (wid & 1) * 64;
  const int aoff0 = (wm + fr) * 32 + fq * 8;
  const int boff0 = (wn + fr) * 32 + fq * 8;
  for (int k0 = 0; k0 < K; k0 += 32) {
    __syncthreads();                       // prev-iter LDS reads done
    gload16(pa0 + k0, &As[tid * 8]);
    gload16(pa1 + k0, &As[2048 + tid * 8]);
    gload16(pb0 + k0, &Bs[tid * 8]);
    gload16(pb1 + k0, &Bs[2048 + tid * 8]);
    __syncthreads();                       // drains vmcnt(0): LDS ready
    short8 av[4], bv[4];
#pragma unroll
    for (int i = 0; i < 4; i++) av[i] = *(const short8*)&As[aoff0 + i * 16 * 32];
#pragma unroll
    for (int i = 0; i < 4; i++) bv[i] = *(const short8*)&Bs[boff0 + i * 16 * 32];
#pragma unroll
    for (int i = 0; i < 4; i++)
#pragma unroll
      for (int j = 0; j < 4; j++)
        acc[i][j] = __builtin_amdgcn_mfma_f32_16x16x32_bf16(av[i], bv[j], acc[i][j], 0, 0, 0);
  }

  if constexpr (EPI == 0) {
    unsigned short* xpb = (unsigned short*)vp0;
    float* bcI = (float*)vp1;     // [8192][64][2]
#pragma unroll
    for (int i = 0; i < 4; i++) {
#pragma unroll
      for (int j = 0; j < 4; j++) {
        int gc = bn * 128 + wn + j * 16 + fr;
        if (gc >= N) continue;
        float bb = bias[gc];
#pragma unroll
        for (int e = 0; e < 4; e++) {
          int gr = bm * 128 + wm + i * 16 + fq * 4 + e;
          float v = acc[i][j][e] + bb;
          xpb[(size_t)gr * XPW + gc] = f2bf(v);
          if (gc >= 64 && gc < 128)      bcI[((size_t)gr * 64 + gc - 64) * 2 + 0] = v;
          else if (gc >= 128)            bcI[((size_t)gr * 64 + gc - 128) * 2 + 1] = v;
        }
      }
    }
  } else if constexpr (EPI == 2) {
    unsigned short* xib = (unsigned short*)vp0;
    unsigned short* grm = (unsigned short*)vp1;
#pragma unroll
    for (int i = 0; i < 4; i++) {
#pragma unroll
      for (int j = 0; j < 4; j++) {
        int gc = bn * 128 + wn + j * 16 + fr;
        float bb = bias[gc];
#pragma unroll
        for (int e = 0; e < 4; e++) {
          int gr = bm * 128 + wm + i * 16 + fq * 4 + e;
          float v = acc[i][j][e] + bb;
          if (gc < nsilu) xib[(size_t)gr * DI + gc] = f2bf(v);
          else            grm[(size_t)gr * DI + (gc - nsilu)] = f2bf(siluf_(v));
        }
      }
    }
  } else {
    // EPI == 1: dt path with LDS transpose
    unsigned short* dtTh = (unsigned short*)vp0;       // [4][2048][2048] f16
    unsigned* dxgT = (unsigned*)vp1;                   // [4][2048][2048] u32
    const unsigned short* xcb = (const unsigned short*)vp2;
    const unsigned short* grm = (const unsigned short*)vp3;
    // in-place: acc -> dt = softplus(acc + 2*b_dt)
#pragma unroll
    for (int j = 0; j < 4; j++) {
      int gc = bn * 128 + wn + j * 16 + fr;
      float bb2 = 2.f * bias[gc];
#pragma unroll
      for (int i = 0; i < 4; i++)
#pragma unroll
        for (int e = 0; e < 4; e++) {
          float v = acc[i][j][e] + bb2;
          acc[i][j][e] = fmaxf(v, 0.f) + log1pf(__expf(-fabsf(v)));
        }
    }
    __shared__ char ebuf[4 * 64 * 36 * 4];             // 36 KiB, reused
    unsigned short* hbuf = (unsigned short*)ebuf;      // [256][36] f16   (row = b*64+dl)
    unsigned* wbuf = (unsigned*)ebuf;                  // [256][36] u32
    const int myc = wn >> 6;                           // wave's d-chunk (0/1)
    const int tbase = wm / 4;                          // 0 or 16
    for (int c = 0; c < 2; ++c) {
      __syncthreads();
      if (myc == c) {
#pragma unroll
        for (int i = 0; i < 4; i++)
#pragma unroll
          for (int j = 0; j < 4; j++) {
            int dl = j * 16 + fr;                      // 0..63
            int t_ = tbase + i * 4 + fq;               // 0..31
#pragma unroll
            for (int e = 0; e < 4; e++)                // e = b index
              hbuf[(e * 64 + dl) * 36 + t_] =
                __builtin_bit_cast(unsigned short, __float2half_rn(acc[i][j][e]));
          }
      }
      __syncthreads();
#pragma unroll
      for (int p = 0; p < 4; ++p) {                    // 256 rows x 32 t (f16)
        int row = p * 64 + (tid >> 2);                 // b = row>>6, dl = row&63
        int t0 = (tid & 3) * 8;
        ushort4 v0 = *(ushort4*)&hbuf[row * 36 + t0];
        ushort4 v1 = *(ushort4*)&hbuf[row * 36 + t0 + 4];
        size_t grow = (size_t)((row >> 6) * DI + bn * 128 + c * 64 + (row & 63));
        *(ushort4*)&dtTh[grow * S_LEN + bm * 32 + t0] = v0;
        *(ushort4*)&dtTh[grow * S_LEN + bm * 32 + t0 + 4] = v1;
      }
      __syncthreads();
      if (myc == c) {
#pragma unroll
        for (int i = 0; i < 4; i++)
#pragma unroll
          for (int j = 0; j < 4; j++) {
            int dl = j * 16 + fr;
            int gc = bn * 128 + wn + j * 16 + fr;
            int t_ = tbase + i * 4 + fq;
#pragma unroll
            for (int e = 0; e < 4; e++) {
              int gr = bm * 128 + wm + i * 16 + fq * 4 + e;
              unsigned short xr = xcb[(size_t)gr * DI + gc];
              unsigned short gg = grm[(size_t)gr * DI + gc];
              float dtx = acc[i][j][e] * bf2f(xr);
              wbuf[(e * 64 + dl) * 36 + t_] = ((unsigned)f2bf(dtx) << 16) | (unsigned)gg;
            }
          }
      }
      __syncthreads();
#pragma unroll
      for (int p = 0; p < 8; ++p) {                    // 256 rows x 32 t (u32)
        int row = p * 32 + (tid >> 3);
        int t0 = (tid & 7) * 4;
        uint4 v = *(uint4*)&wbuf[row * 36 + t0];
        size_t grow = (size_t)((row >> 6) * DI + bn * 128 + c * 64 + (row & 63));
        *(uint4*)&dxgT[grow * S_LEN + bm * 32 + t0] = v;
      }
    }
  }
}

// ---------------- causal depthwise conv (K=4) + silu, bf16 in/out -------------
__global__ __launch_bounds__(256) void conv_k(const unsigned short* __restrict__ xib,
                                              const float* __restrict__ cw,
                                              const float* __restrict__ cb,
                                              unsigned short* __restrict__ xcb)
{
  int gid = blockIdx.x * 256 + threadIdx.x;      // 4,194,304 groups of 4 d
  int d4 = (gid & 511) * 4;
  int r  = gid >> 9;
  const unsigned short* p = xib + (size_t)r * DI + d4;
  ushort4 z4; z4.x = z4.y = z4.z = z4.w = 0;
  ushort4 t0 = *(const ushort4*)p;
  ushort4 t1 = (r >= 4)  ? *(const ushort4*)(p - 4  * DI) : z4;
  ushort4 t2 = (r >= 8)  ? *(const ushort4*)(p - 8  * DI) : z4;
  ushort4 t3 = (r >= 12) ? *(const ushort4*)(p - 12 * DI) : z4;
  ushort4 o;
  unsigned short tv0[4] = {t0.x,t0.y,t0.z,t0.w};
  unsigned short tv1[4] = {t1.x,t1.y,t1.z,t1.w};
  unsigned short tv2[4] = {t2.x,t2.y,t2.z,t2.w};
  unsigned short tv3[4] = {t3.x,t3.y,t3.z,t3.w};
  unsigned short ov[4];
#pragma unroll
  for (int j = 0; j < 4; ++j) {
    int d = d4 + j;
    float4 w = *(const float4*)&cw[d * 4];
    float s = cb[d];
    s = fmaf(w.w, bf2f(tv0[j]), s);
    s = fmaf(w.z, bf2f(tv1[j]), s);
    s = fmaf(w.y, bf2f(tv2[j]), s);
    s = fmaf(w.x, bf2f(tv3[j]), s);
    ov[j] = f2bf(siluf_(s));
  }
  o.x = ov[0]; o.y = ov[1]; o.z = ov[2]; o.w = ov[3];
  *(ushort4*)(xcb + (size_t)r * DI + d4) = o;
}

// ---------------- sxg[b][d] = sum_t x_conv*g  (D-term) ----------------
__global__ __launch_bounds__(256) void sxg_k(const unsigned short* __restrict__ xcb,
                                             const unsigned short* __restrict__ grm,
                                             float* __restrict__ sxg)
{
  int d = blockIdx.x * 1024 + threadIdx.x * 4;
  int b = blockIdx.y;
  int t0 = blockIdx.z * 128;
  float a0 = 0.f, a1 = 0.f, a2 = 0.f, a3 = 0.f;
  for (int tt = 0; tt < 128; ++tt) {
    size_t r = (size_t)(t0 + tt) * 4 + b;
    ushort4 xv = *(const ushort4*)&xcb[r * DI + d];
    ushort4 gv = *(const ushort4*)&grm[r * DI + d];
    a0 = fmaf(bf2f(xv.x), bf2f(gv.x), a0);
    a1 = fmaf(bf2f(xv.y), bf2f(gv.y), a1);
    a2 = fmaf(bf2f(xv.z), bf2f(gv.z), a2);
    a3 = fmaf(bf2f(xv.w), bf2f(gv.w), a3);
  }
  atomicAdd(&sxg[b * DI + d + 0], a0);
  atomicAdd(&sxg[b * DI + d + 1], a1);
  atomicAdd(&sxg[b * DI + d + 2], a2);
  atomicAdd(&sxg[b * DI + d + 3], a3);
}

// ------- selective scan: 2 channels/wave, scalar streams via s_load -----------
__global__ __launch_bounds__(256) void scan_k(const unsigned short* __restrict__ dtTh,
                                              const unsigned* __restrict__ dxgT,
                                              const float* __restrict__ bcI,
                                              const float* __restrict__ A_log,
                                              const float* __restrict__ state_in,
                                              float* __restrict__ accbuf,
                                              float* __restrict__ state_out)
{
  const int tid  = threadIdx.x;
  const int lane = tid & 63;
  const int gw = __builtin_amdgcn_readfirstlane(blockIdx.x * 4 + (tid >> 6));  // 0..4095
  const int b  = gw >> 10;
  const int d0 = (gw & 1023) * 2;
  const float LOG2E = 1.4426950408889634f;
  float a20 = -__expf(A_log[(size_t)d0 * DS + lane]) * LOG2E;
  float a21 = -__expf(A_log[(size_t)(d0 + 1) * DS + lane]) * LOG2E;
  float st0 = state_in[((size_t)(b * DI + d0)) * DS + lane];
  float st1 = state_in[((size_t)(b * DI + d0 + 1)) * DS + lane];
  const unsigned* pdh0 = (const unsigned*)dtTh + (size_t)(b * DI + d0) * (S_LEN / 2);
  const unsigned* pdh1 = pdh0 + (S_LEN / 2);
  const unsigned* pdx0 = dxgT + (size_t)(b * DI + d0) * S_LEN;
  const unsigned* pdx1 = pdx0 + S_LEN;
  const float* pbc = bcI + ((size_t)b * 64 + lane) * 2;
  float acc0 = 0.f, acc1 = 0.f;
#pragma unroll 4
  for (int th = 0; th < S_LEN / 2; ++th) {
    unsigned dp0 = pdh0[th], dp1 = pdh1[th];
#pragma unroll
    for (int h = 0; h < 2; ++h) {
      int t = th * 2 + h;
      float2 bc = *(const float2*)(pbc + (size_t)t * 512);
      unsigned dx0 = pdx0[t], dx1 = pdx1[t];
      float dts0 = __half2float(__builtin_bit_cast(__half, (unsigned short)(h ? (dp0 >> 16) : (dp0 & 0xffffu))));
      float dts1 = __half2float(__builtin_bit_cast(__half, (unsigned short)(h ? (dp1 >> 16) : (dp1 & 0xffffu))));
      float dxs0 = __builtin_bit_cast(float, dx0 & 0xffff0000u);
      float gs0  = __builtin_bit_cast(float, dx0 << 16);
      float dxs1 = __builtin_bit_cast(float, dx1 & 0xffff0000u);
      float gs1  = __builtin_bit_cast(float, dx1 << 16);
      float dA0 = __builtin_amdgcn_exp2f(dts0 * a20);
      float dA1 = __builtin_amdgcn_exp2f(dts1 * a21);
      st0 = fmaf(st0, dA0, dxs0 * bc.x);
      st1 = fmaf(st1, dA1, dxs1 * bc.x);
      acc0 = fmaf(st0 * bc.y, gs0, acc0);
      acc1 = fmaf(st1 * bc.y, gs1, acc1);
    }
  }
  state_out[((size_t)(b * DI + d0)) * DS + lane] = st0;
  state_out[((size_t)(b * DI + d0 + 1)) * DS + lane] = st1;
#pragma unroll
  for (int m = 32; m; m >>= 1) {
    acc0 += __shfl_xor(acc0, m, 64);
    acc1 += __shfl_xor(acc1, m, 64);
  }
  if (lane == 0) {
    accbuf[b * DI + d0] = acc0;
    accbuf[b * DI + d0 + 1] = acc1;
  }
}

// ---------------- out = ((acc + D*sxg)/S) @ W_out^T + b_out ----------------
__global__ __launch_bounds__(256) void out_gemm_k(const float* __restrict__ accb,
                                                  const float* __restrict__ sxg,
                                                  const float* __restrict__ Dv,
                                                  const float* __restrict__ W_out,
                                                  const float* __restrict__ b_out,
                                                  float* __restrict__ outpre)
{
  int b = blockIdx.y;
  int m = blockIdx.x * 8 + (threadIdx.x >> 5);
  int dl = threadIdx.x & 31;
  const float* wr = W_out + (size_t)m * DI;
  const float* ac = accb + b * DI;
  const float* sx = sxg + b * DI;
  float p = 0.f;
  for (int dd = dl; dd < DI; dd += 32) {
    float av = fmaf(Dv[dd], sx[dd], ac[dd]);
    p = fmaf(wr[dd], av, p);
  }
#pragma unroll
  for (int s = 16; s; s >>= 1) p += __shfl_xor(p, s, 32);
  if (dl == 0) outpre[b * DM + m] = p * (1.f / 2048.f) + b_out[m];
}

// ---------------- layernorm over d_model ----------------
__global__ __launch_bounds__(256) void ln_k(const float* __restrict__ outpre,
                                            const float* __restrict__ g,
                                            const float* __restrict__ bta,
                                            float* __restrict__ dout)
{
  int b = blockIdx.x;
  const float* row = outpre + b * DM;
  float s = 0.f, s2 = 0.f, vv[4];
#pragma unroll
  for (int i = 0; i < 4; i++) {
    float v = row[threadIdx.x + i * 256];
    vv[i] = v; s += v; s2 += v * v;
  }
#pragma unroll
  for (int m = 32; m; m >>= 1) { s += __shfl_xor(s, m, 64); s2 += __shfl_xor(s2, m, 64); }
  __shared__ float rs[4], rs2[4];
  int w = threadIdx.x >> 6;
  if ((threadIdx.x & 63) == 0) { rs[w] = s; rs2[w] = s2; }
  __syncthreads();
  float S = rs[0] + rs[1] + rs[2] + rs[3];
  float S2 = rs2[0] + rs2[1] + rs2[2] + rs2[3];
  float mu = S * (1.f / 1024.f);
  float var = S2 * (1.f / 1024.f) - mu * mu;
  float inv = rsqrtf(var + 1e-5f);
#pragma unroll
  for (int i = 0; i < 4; i++) {
    int c = threadIdx.x + i * 256;
    dout[b * DM + c] = (vv[i] - mu) * inv * g[c] + bta[c];
  }
}

extern "C" void kernel_launch(void* const* d_in, const int* in_sizes, int n_in,
                              void* d_out, int out_size, void* d_ws, size_t ws_size,
                              hipStream_t stream)
{
  const float* x      = (const float*)d_in[0];
  const float* state0 = (const float*)d_in[1];
  const float* W_in   = (const float*)d_in[2];
  const float* b_in   = (const float*)d_in[3];
  const float* conv_w = (const float*)d_in[4];
  const float* conv_b = (const float*)d_in[5];
  const float* W_xp   = (const float*)d_in[6];
  const float* b_xp   = (const float*)d_in[7];
  const float* W_dt   = (const float*)d_in[8];
  const float* b_dt   = (const float*)d_in[9];
  const float* A_log  = (const float*)d_in[10];
  const float* Dvec   = (const float*)d_in[11];
  const float* W_out  = (const float*)d_in[12];
  const float* b_out  = (const float*)d_in[13];
  const float* ln_g   = (const float*)d_in[14];
  const float* ln_b   = (const float*)d_in[15];
  float* out = (float*)d_out;   // [4*1024] out, then [4*2048*64] final_state

  const size_t MB = 1024 * 1024;
  char* ws = (char*)d_ws;
  unsigned short* xib  = (unsigned short*)(ws + 0);          // 32MB [8192][2048] bf16 (dead after conv)
  unsigned short* dtTh = (unsigned short*)(ws + 0);          // 32MB [4][2048][2048] f16 (overlays xib)
  unsigned short* grm  = (unsigned short*)(ws + 32  * MB);   // 32MB gate bf16 rm
  unsigned short* xcb  = (unsigned short*)(ws + 64  * MB);   // 32MB x_conv bf16 rm
  unsigned*       dxgT = (unsigned*)(ws + 96 * MB);          // 64MB [4][2048][2048] u32
  unsigned short* xb   = (unsigned short*)(ws + 96  * MB);   // 16MB x bf16 (dead after gemm_in)
  unsigned short* wbin = (unsigned short*)(ws + 112 * MB);   // 8MB  W_in bf16 (dead after gemm_in)
  unsigned short* xpb  = (unsigned short*)(ws + 160 * MB);   // 3MB  [8192][192] bf16
  float*          bcI  = (float*)(ws + 163 * MB);            // 4MB  [8192][64] float2
  unsigned short* wbxp = (unsigned short*)(ws + 167 * MB);   // 768KB
  unsigned short* wbdt = (unsigned short*)(ws + 167 * MB + 786432); // 256KB
  float*          sxg    = (float*)(ws + 168 * MB);          // 32KB [4][2048]
  float*          accb   = (float*)(ws + 168 * MB + 32768);  // 32KB [4][2048]
  float*          outpre = (float*)(ws + 168 * MB + 65536);  // 16KB [4][1024]

  cvt_bf16_k<<<8192, 256, 0, stream>>>(x,    xb,   8388608);
  cvt_bf16_k<<<4096, 256, 0, stream>>>(W_in, wbin, 4194304);
  cvt_bf16_k<<<384,  256, 0, stream>>>(W_xp, wbxp, 393216);
  cvt_bf16_k<<<128,  256, 0, stream>>>(W_dt, wbdt, 131072);
  hipMemsetAsync(sxg, 0, 4 * DI * sizeof(float), stream);
  // xz = x @ W_in^T + b_in; cols<2048 -> xib bf16; cols>=2048 -> silu -> grm bf16
  gemm_bt<2><<<dim3(64, 32), 256, 0, stream>>>(xb, wbin, b_in, 4096, 1024, 1024, 1024,
                                               xib, grm, nullptr, nullptr, 2048);
  conv_k<<<16384, 256, 0, stream>>>(xib, conv_w, conv_b, xcb);
  sxg_k<<<dim3(2, 4, 16), 256, 0, stream>>>(xcb, grm, sxg);
  // xp = x_conv @ W_xp^T + b_xp -> xpb bf16 + bcI float2
  gemm_bt<0><<<dim3(64, 2), 256, 0, stream>>>(xcb, wbxp, b_xp, 192, 2048, 2048, 2048,
                                              xpb, bcI, nullptr, nullptr, 0);
  // dt path: softplus GEMM -> dtTh f16 + dxgT u32 (LDS transpose epilogue)
  gemm_bt<1><<<dim3(64, 16), 256, 0, stream>>>(xpb, wbdt, b_dt, 2048, 64, XPW, 64,
                                               dtTh, dxgT, xcb, grm, 0);
  scan_k<<<1024, 256, 0, stream>>>(dtTh, dxgT, bcI, A_log, state0, accb, out + 4096);
  out_gemm_k<<<dim3(128, 4), 256, 0, stream>>>(accb, sxg, Dvec, W_out, b_out, outpre);
  ln_k<<<4, 256, 0, stream>>>(outpre, ln_g, ln_b, out);
}

// Round 4
// 689.302 us; speedup vs baseline: 1.3367x; 1.0063x over previous
//
#include <hip/hip_runtime.h>
#include <hip/hip_fp16.h>

typedef __attribute__((ext_vector_type(8))) short short8;
typedef __attribute__((ext_vector_type(4))) float f32x4;
typedef __attribute__((ext_vector_type(2))) float f32x2;

#define S_LEN 2048
#define BATCH 4
#define DM 1024
#define DI 2048
#define DS 64
#define DTR 64
#define XPW 192   // dt_rank + 2*d_state

__device__ __forceinline__ unsigned short f2bf(float f){
  unsigned u = __builtin_bit_cast(unsigned, f);
  u += 0x7fffu + ((u >> 16) & 1u);
  return (unsigned short)(u >> 16);
}
__device__ __forceinline__ float bf2f(unsigned short h){
  unsigned u = ((unsigned)h) << 16;
  return __builtin_bit_cast(float, u);
}
__device__ __forceinline__ void gload16(const void* g, void* l){
  __builtin_amdgcn_global_load_lds((const __attribute__((address_space(1))) void*)g,
                                   (__attribute__((address_space(3))) void*)l, 16, 0, 0);
}
__device__ __forceinline__ float siluf_(float v){ return v / (1.f + __expf(-v)); }

// ---------------- fused f32 -> bf16 convert (4 segments) ----------------
__global__ __launch_bounds__(256) void cvt_all_k(const float* __restrict__ i0, unsigned short* __restrict__ o0,
                                                 const float* __restrict__ i1, unsigned short* __restrict__ o1,
                                                 const float* __restrict__ i2, unsigned short* __restrict__ o2,
                                                 const float* __restrict__ i3, unsigned short* __restrict__ o3)
{
  int bid = blockIdx.x;
  const float* in; unsigned short* out; int base;
  if (bid < 8192)       { in = i0; out = o0; base = bid; }
  else if (bid < 12288) { in = i1; out = o1; base = bid - 8192; }
  else if (bid < 12672) { in = i2; out = o2; base = bid - 12288; }
  else                  { in = i3; out = o3; base = bid - 12672; }
  int i = (base * 256 + threadIdx.x) * 4;
  float4 v = *(const float4*)(in + i);
  ushort4 o;
  o.x = f2bf(v.x); o.y = f2bf(v.y); o.z = f2bf(v.z); o.w = f2bf(v.w);
  *(ushort4*)(out + i) = o;
}

// ---------------- bf16 MFMA GEMM, C = A[M,K] * B[N,K]^T + bias ----------------
// 128x128 tile, BK=32, 4 waves (2x2), 16x16x32 MFMA, global_load_lds width=16.
// EPI 0 (xp):  write Cb=xpb bf16 rm; cols [64,128)->bcI.x, [128,192)->bcI.y (f32).
// EPI 1 (dt):  dt=softplus(v+2*bias); LDS-transpose ->
//              dtP u32 [b][pair][t] = f16(dt_d0)|f16(dt_d1)<<16
//              dxgP u32 [b][pair][t][ch] = (bf16(dt*x)<<16)|bf16(g)
// EPI 2 (in):  cols<nsilu -> xib bf16 rm; cols>=nsilu -> g_rm = bf16(silu(v)) rm.
template<int EPI>
__global__ __launch_bounds__(256)
void gemm_bt(const unsigned short* __restrict__ A, const unsigned short* __restrict__ B,
             const float* __restrict__ bias,
             int N, int K, int lda, int ldb,
             void* __restrict__ vp0, void* __restrict__ vp1,
             const void* __restrict__ vp2, const void* __restrict__ vp3, int nsilu)
{
  __shared__ unsigned short As[128 * 32];
  __shared__ unsigned short Bs[128 * 32];
  const int tid  = threadIdx.x;
  const int lane = tid & 63;
  const int wid  = tid >> 6;
  const int bm = blockIdx.x, bn = blockIdx.y;
  const int r0 = tid >> 2;           // 0..63
  const int c0 = (tid & 3) * 8;      // 0,8,16,24
  int brow0 = bn * 128 + r0;        if (brow0 > N - 1) brow0 = N - 1;
  int brow1 = bn * 128 + 64 + r0;   if (brow1 > N - 1) brow1 = N - 1;
  const unsigned short* pa0 = A + (size_t)(bm * 128 + r0) * lda + c0;
  const unsigned short* pa1 = A + (size_t)(bm * 128 + 64 + r0) * lda + c0;
  const unsigned short* pb0 = B + (size_t)brow0 * ldb + c0;
  const unsigned short* pb1 = B + (size_t)brow1 * ldb + c0;
  f32x4 acc[4][4] = {};
  const int fr = lane & 15, fq = lane >> 4;
  const int wm = (wid >> 1) * 64, wn = (wid & 1) * 64;
  const int aoff0 = (wm + fr) * 32 + fq * 8;
  const int boff0 = (wn + fr) * 32 + fq * 8;
  for (int k0 = 0; k0 < K; k0 += 32) {
    __syncthreads();                       // prev-iter LDS reads done
    gload16(pa0 + k0, &As[tid * 8]);
    gload16(pa1 + k0, &As[2048 + tid * 8]);
    gload16(pb0 + k0, &Bs[tid * 8]);
    gload16(pb1 + k0, &Bs[2048 + tid * 8]);
    __syncthreads();                       // drains vmcnt(0): LDS ready
    short8 av[4], bv[4];
#pragma unroll
    for (int i = 0; i < 4; i++) av[i] = *(const short8*)&As[aoff0 + i * 16 * 32];
#pragma unroll
    for (int i = 0; i < 4; i++) bv[i] = *(const short8*)&Bs[boff0 + i * 16 * 32];
#pragma unroll
    for (int i = 0; i < 4; i++)
#pragma unroll
      for (int j = 0; j < 4; j++)
        acc[i][j] = __builtin_amdgcn_mfma_f32_16x16x32_bf16(av[i], bv[j], acc[i][j], 0, 0, 0);
  }

  if constexpr (EPI == 0) {
    unsigned short* xpb = (unsigned short*)vp0;
    float* bcI = (float*)vp1;     // [8192][64][2]
#pragma unroll
    for (int i = 0; i < 4; i++) {
#pragma unroll
      for (int j = 0; j < 4; j++) {
        int gc = bn * 128 + wn + j * 16 + fr;
        if (gc >= N) continue;
        float bb = bias[gc];
#pragma unroll
        for (int e = 0; e < 4; e++) {
          int gr = bm * 128 + wm + i * 16 + fq * 4 + e;
          float v = acc[i][j][e] + bb;
          xpb[(size_t)gr * XPW + gc] = f2bf(v);
          if (gc >= 64 && gc < 128)      bcI[((size_t)gr * 64 + gc - 64) * 2 + 0] = v;
          else if (gc >= 128)            bcI[((size_t)gr * 64 + gc - 128) * 2 + 1] = v;
        }
      }
    }
  } else if constexpr (EPI == 2) {
    unsigned short* xib = (unsigned short*)vp0;
    unsigned short* grm = (unsigned short*)vp1;
#pragma unroll
    for (int i = 0; i < 4; i++) {
#pragma unroll
      for (int j = 0; j < 4; j++) {
        int gc = bn * 128 + wn + j * 16 + fr;
        float bb = bias[gc];
#pragma unroll
        for (int e = 0; e < 4; e++) {
          int gr = bm * 128 + wm + i * 16 + fq * 4 + e;
          float v = acc[i][j][e] + bb;
          if (gc < nsilu) xib[(size_t)gr * DI + gc] = f2bf(v);
          else            grm[(size_t)gr * DI + (gc - nsilu)] = f2bf(siluf_(v));
        }
      }
    }
  } else {
    // EPI == 1: dt path with LDS transpose into pair-interleaved streams
    unsigned* dtP  = (unsigned*)vp0;                   // [4][1024][2048] u32
    unsigned* dxgP = (unsigned*)vp1;                   // [4][1024][2048][2] u32
    const unsigned short* xcb = (const unsigned short*)vp2;
    const unsigned short* grm = (const unsigned short*)vp3;
    // in-place: acc -> dt = softplus(acc + 2*b_dt)
#pragma unroll
    for (int j = 0; j < 4; j++) {
      int gc = bn * 128 + wn + j * 16 + fr;
      float bb2 = 2.f * bias[gc];
#pragma unroll
      for (int i = 0; i < 4; i++)
#pragma unroll
        for (int e = 0; e < 4; e++) {
          float v = acc[i][j][e] + bb2;
          acc[i][j][e] = fmaxf(v, 0.f) + log1pf(__expf(-fabsf(v)));
        }
    }
    __shared__ char ebuf[4 * 64 * 36 * 4];             // 36 KiB, reused
    unsigned short* hbuf = (unsigned short*)ebuf;      // [256][36] f16   (row = b*64+dl)
    unsigned* wbuf = (unsigned*)ebuf;                  // [256][36] u32
    const int myc = wn >> 6;                           // wave's d-chunk (0/1)
    const int tbase = wm / 4;                          // 0 or 16
    for (int c = 0; c < 2; ++c) {
      __syncthreads();
      if (myc == c) {
#pragma unroll
        for (int i = 0; i < 4; i++)
#pragma unroll
          for (int j = 0; j < 4; j++) {
            int dl = j * 16 + fr;                      // 0..63
            int t_ = tbase + i * 4 + fq;               // 0..31
#pragma unroll
            for (int e = 0; e < 4; e++)                // e = b index
              hbuf[(e * 64 + dl) * 36 + t_] =
                __builtin_bit_cast(unsigned short, __float2half_rn(acc[i][j][e]));
          }
      }
      __syncthreads();
#pragma unroll
      for (int k = 0; k < 4; ++k) {                    // dtP: 1024 uint4 words
        int gidx = tid + k * 256;
        int t0 = (gidx & 7) * 4;
        int pl = (gidx >> 3) & 31;
        int e  = gidx >> 8;
        const unsigned short* r0 = &hbuf[(e * 64 + 2 * pl)     * 36 + t0];
        const unsigned short* r1 = &hbuf[(e * 64 + 2 * pl + 1) * 36 + t0];
        uint4 o;
        o.x = (unsigned)r0[0] | ((unsigned)r1[0] << 16);
        o.y = (unsigned)r0[1] | ((unsigned)r1[1] << 16);
        o.z = (unsigned)r0[2] | ((unsigned)r1[2] << 16);
        o.w = (unsigned)r0[3] | ((unsigned)r1[3] << 16);
        size_t pg = (size_t)e * 1024 + bn * 64 + c * 32 + pl;
        *(uint4*)&dtP[pg * S_LEN + bm * 32 + t0] = o;
      }
      __syncthreads();
      if (myc == c) {
#pragma unroll
        for (int i = 0; i < 4; i++)
#pragma unroll
          for (int j = 0; j < 4; j++) {
            int dl = j * 16 + fr;
            int gc = bn * 128 + wn + j * 16 + fr;
            int t_ = tbase + i * 4 + fq;
#pragma unroll
            for (int e = 0; e < 4; e++) {
              int gr = bm * 128 + wm + i * 16 + fq * 4 + e;
              unsigned short xr = xcb[(size_t)gr * DI + gc];
              unsigned short gg = grm[(size_t)gr * DI + gc];
              float dtx = acc[i][j][e] * bf2f(xr);
              wbuf[(e * 64 + dl) * 36 + t_] = ((unsigned)f2bf(dtx) << 16) | (unsigned)gg;
            }
          }
      }
      __syncthreads();
#pragma unroll
      for (int k = 0; k < 8; ++k) {                    // dxgP: 2048 uint4 words
        int gidx = tid + k * 256;
        int t0 = (gidx & 15) * 2;
        int pl = (gidx >> 4) & 31;
        int e  = gidx >> 9;
        const unsigned* w0 = &wbuf[(e * 64 + 2 * pl)     * 36];
        const unsigned* w1 = &wbuf[(e * 64 + 2 * pl + 1) * 36];
        uint4 o;
        o.x = w0[t0]; o.y = w1[t0]; o.z = w0[t0 + 1]; o.w = w1[t0 + 1];
        size_t pg = (size_t)e * 1024 + bn * 64 + c * 32 + pl;
        *(uint4*)&dxgP[(pg * S_LEN + bm * 32 + t0) * 2] = o;
      }
    }
  }
}

// ---------------- causal depthwise conv (K=4) + silu, bf16 in/out -------------
__global__ __launch_bounds__(256) void conv_k(const unsigned short* __restrict__ xib,
                                              const float* __restrict__ cw,
                                              const float* __restrict__ cb,
                                              unsigned short* __restrict__ xcb)
{
  int gid = blockIdx.x * 256 + threadIdx.x;      // 4,194,304 groups of 4 d
  int d4 = (gid & 511) * 4;
  int r  = gid >> 9;
  const unsigned short* p = xib + (size_t)r * DI + d4;
  ushort4 z4; z4.x = z4.y = z4.z = z4.w = 0;
  ushort4 t0 = *(const ushort4*)p;
  ushort4 t1 = (r >= 4)  ? *(const ushort4*)(p - 4  * DI) : z4;
  ushort4 t2 = (r >= 8)  ? *(const ushort4*)(p - 8  * DI) : z4;
  ushort4 t3 = (r >= 12) ? *(const ushort4*)(p - 12 * DI) : z4;
  ushort4 o;
  unsigned short tv0[4] = {t0.x,t0.y,t0.z,t0.w};
  unsigned short tv1[4] = {t1.x,t1.y,t1.z,t1.w};
  unsigned short tv2[4] = {t2.x,t2.y,t2.z,t2.w};
  unsigned short tv3[4] = {t3.x,t3.y,t3.z,t3.w};
  unsigned short ov[4];
#pragma unroll
  for (int j = 0; j < 4; ++j) {
    int d = d4 + j;
    float4 w = *(const float4*)&cw[d * 4];
    float s = cb[d];
    s = fmaf(w.w, bf2f(tv0[j]), s);
    s = fmaf(w.z, bf2f(tv1[j]), s);
    s = fmaf(w.y, bf2f(tv2[j]), s);
    s = fmaf(w.x, bf2f(tv3[j]), s);
    ov[j] = f2bf(siluf_(s));
  }
  o.x = ov[0]; o.y = ov[1]; o.z = ov[2]; o.w = ov[3];
  *(ushort4*)(xcb + (size_t)r * DI + d4) = o;
}

// ---------------- sxg[b][d] = sum_t x_conv*g  (D-term) ----------------
__global__ __launch_bounds__(256) void sxg_k(const unsigned short* __restrict__ xcb,
                                             const unsigned short* __restrict__ grm,
                                             float* __restrict__ sxg)
{
  int d = blockIdx.x * 1024 + threadIdx.x * 4;
  int b = blockIdx.y;
  int t0 = blockIdx.z * 32;
  float a0 = 0.f, a1 = 0.f, a2 = 0.f, a3 = 0.f;
  for (int tt = 0; tt < 32; ++tt) {
    size_t r = (size_t)(t0 + tt) * 4 + b;
    ushort4 xv = *(const ushort4*)&xcb[r * DI + d];
    ushort4 gv = *(const ushort4*)&grm[r * DI + d];
    a0 = fmaf(bf2f(xv.x), bf2f(gv.x), a0);
    a1 = fmaf(bf2f(xv.y), bf2f(gv.y), a1);
    a2 = fmaf(bf2f(xv.z), bf2f(gv.z), a2);
    a3 = fmaf(bf2f(xv.w), bf2f(gv.w), a3);
  }
  atomicAdd(&sxg[b * DI + d + 0], a0);
  atomicAdd(&sxg[b * DI + d + 1], a1);
  atomicAdd(&sxg[b * DI + d + 2], a2);
  atomicAdd(&sxg[b * DI + d + 3], a3);
}

// ------- selective scan: 2 channels/wave (packed f32), lane = n ---------------
__global__ __launch_bounds__(256) void scan_k(const unsigned* __restrict__ dtP,
                                              const unsigned* __restrict__ dxgP,
                                              const float* __restrict__ bcI,
                                              const float* __restrict__ A_log,
                                              const float* __restrict__ state_in,
                                              float* __restrict__ accbuf,
                                              float* __restrict__ state_out)
{
  const int tid  = threadIdx.x;
  const int lane = tid & 63;
  const int gp = __builtin_amdgcn_readfirstlane(blockIdx.x * 4 + (tid >> 6));  // 0..4095
  const int b  = gp >> 10;
  const int p  = gp & 1023;
  const int d0 = p * 2;
  const float LOG2E = 1.4426950408889634f;
  f32x2 a2, st, acc = {0.f, 0.f};
  a2.x = -__expf(A_log[(size_t)d0 * DS + lane]) * LOG2E;
  a2.y = -__expf(A_log[(size_t)(d0 + 1) * DS + lane]) * LOG2E;
  st.x = state_in[((size_t)(b * DI + d0)) * DS + lane];
  st.y = state_in[((size_t)(b * DI + d0 + 1)) * DS + lane];
  const unsigned* pdt = dtP + (size_t)gp * S_LEN;
  const unsigned* pdx = dxgP + (size_t)gp * S_LEN * 2;
  const float* pbc = bcI + ((size_t)b * 64 + lane) * 2;
#pragma unroll 8
  for (int t = 0; t < S_LEN; ++t) {
    unsigned dtw = pdt[t];
    uint2 dx2 = *(const uint2*)(pdx + t * 2);
    float2 bc = *(const float2*)(pbc + (size_t)t * 512);
    f32x2 dts;
    dts.x = __half2float(__builtin_bit_cast(__half, (unsigned short)(dtw & 0xffffu)));
    dts.y = __half2float(__builtin_bit_cast(__half, (unsigned short)(dtw >> 16)));
    f32x2 dxs, gs;
    dxs.x = __builtin_bit_cast(float, dx2.x & 0xffff0000u);
    dxs.y = __builtin_bit_cast(float, dx2.y & 0xffff0000u);
    gs.x  = __builtin_bit_cast(float, dx2.x << 16);
    gs.y  = __builtin_bit_cast(float, dx2.y << 16);
    f32x2 arg = dts * a2;                       // v_pk_mul_f32
    f32x2 dA;
    dA.x = __builtin_amdgcn_exp2f(arg.x);
    dA.y = __builtin_amdgcn_exp2f(arg.y);
    f32x2 bx = {bc.x, bc.x}, by = {bc.y, bc.y};
    f32x2 u = dxs * bx;                         // v_pk_mul_f32
    st = __builtin_elementwise_fma(st, dA, u);  // v_pk_fma_f32
    f32x2 tmp = st * by;                        // v_pk_mul_f32
    acc = __builtin_elementwise_fma(tmp, gs, acc);
  }
  state_out[((size_t)(b * DI + d0)) * DS + lane] = st.x;
  state_out[((size_t)(b * DI + d0 + 1)) * DS + lane] = st.y;
  float a0 = acc.x, a1 = acc.y;
#pragma unroll
  for (int m = 32; m; m >>= 1) {
    a0 += __shfl_xor(a0, m, 64);
    a1 += __shfl_xor(a1, m, 64);
  }
  if (lane == 0) {
    accbuf[b * DI + d0] = a0;
    accbuf[b * DI + d0 + 1] = a1;
  }
}

// ---------------- out = ((acc + D*sxg)/S) @ W_out^T + b_out ----------------
__global__ __launch_bounds__(256) void out_gemm_k(const float* __restrict__ accb,
                                                  const float* __restrict__ sxg,
                                                  const float* __restrict__ Dv,
                                                  const float* __restrict__ W_out,
                                                  const float* __restrict__ b_out,
                                                  float* __restrict__ outpre)
{
  int b = blockIdx.y;
  int m = blockIdx.x * 8 + (threadIdx.x >> 5);
  int dl = threadIdx.x & 31;
  const float* wr = W_out + (size_t)m * DI;
  const float* ac = accb + b * DI;
  const float* sx = sxg + b * DI;
  float p = 0.f;
  for (int dd = dl; dd < DI; dd += 32) {
    float av = fmaf(Dv[dd], sx[dd], ac[dd]);
    p = fmaf(wr[dd], av, p);
  }
#pragma unroll
  for (int s = 16; s; s >>= 1) p += __shfl_xor(p, s, 32);
  if (dl == 0) outpre[b * DM + m] = p * (1.f / 2048.f) + b_out[m];
}

// ---------------- layernorm over d_model ----------------
__global__ __launch_bounds__(256) void ln_k(const float* __restrict__ outpre,
                                            const float* __restrict__ g,
                                            const float* __restrict__ bta,
                                            float* __restrict__ dout)
{
  int b = blockIdx.x;
  const float* row = outpre + b * DM;
  float s = 0.f, s2 = 0.f, vv[4];
#pragma unroll
  for (int i = 0; i < 4; i++) {
    float v = row[threadIdx.x + i * 256];
    vv[i] = v; s += v; s2 += v * v;
  }
#pragma unroll
  for (int m = 32; m; m >>= 1) { s += __shfl_xor(s, m, 64); s2 += __shfl_xor(s2, m, 64); }
  __shared__ float rs[4], rs2[4];
  int w = threadIdx.x >> 6;
  if ((threadIdx.x & 63) == 0) { rs[w] = s; rs2[w] = s2; }
  __syncthreads();
  float S = rs[0] + rs[1] + rs[2] + rs[3];
  float S2 = rs2[0] + rs2[1] + rs2[2] + rs2[3];
  float mu = S * (1.f / 1024.f);
  float var = S2 * (1.f / 1024.f) - mu * mu;
  float inv = rsqrtf(var + 1e-5f);
#pragma unroll
  for (int i = 0; i < 4; i++) {
    int c = threadIdx.x + i * 256;
    dout[b * DM + c] = (vv[i] - mu) * inv * g[c] + bta[c];
  }
}

extern "C" void kernel_launch(void* const* d_in, const int* in_sizes, int n_in,
                              void* d_out, int out_size, void* d_ws, size_t ws_size,
                              hipStream_t stream)
{
  const float* x      = (const float*)d_in[0];
  const float* state0 = (const float*)d_in[1];
  const float* W_in   = (const float*)d_in[2];
  const float* b_in   = (const float*)d_in[3];
  const float* conv_w = (const float*)d_in[4];
  const float* conv_b = (const float*)d_in[5];
  const float* W_xp   = (const float*)d_in[6];
  const float* b_xp   = (const float*)d_in[7];
  const float* W_dt   = (const float*)d_in[8];
  const float* b_dt   = (const float*)d_in[9];
  const float* A_log  = (const float*)d_in[10];
  const float* Dvec   = (const float*)d_in[11];
  const float* W_out  = (const float*)d_in[12];
  const float* b_out  = (const float*)d_in[13];
  const float* ln_g   = (const float*)d_in[14];
  const float* ln_b   = (const float*)d_in[15];
  float* out = (float*)d_out;   // [4*1024] out, then [4*2048*64] final_state

  const size_t MB = 1024 * 1024;
  char* ws = (char*)d_ws;
  unsigned short* xib  = (unsigned short*)(ws + 0);          // 32MB [8192][2048] bf16 (dead after conv)
  unsigned*       dtP  = (unsigned*)(ws + 0);                // 32MB [4][1024][2048] u32 (overlays xib)
  unsigned short* grm  = (unsigned short*)(ws + 32  * MB);   // 32MB gate bf16 rm
  unsigned short* xcb  = (unsigned short*)(ws + 64  * MB);   // 32MB x_conv bf16 rm
  unsigned*       dxgP = (unsigned*)(ws + 96 * MB);          // 64MB [4][1024][2048][2] u32
  unsigned short* xb   = (unsigned short*)(ws + 96  * MB);   // 16MB x bf16 (dead after gemm_in)
  unsigned short* wbin = (unsigned short*)(ws + 112 * MB);   // 8MB  W_in bf16 (dead after gemm_in)
  unsigned short* xpb  = (unsigned short*)(ws + 160 * MB);   // 3MB  [8192][192] bf16
  float*          bcI  = (float*)(ws + 163 * MB);            // 4MB  [8192][64] float2
  unsigned short* wbxp = (unsigned short*)(ws + 167 * MB);   // 768KB
  unsigned short* wbdt = (unsigned short*)(ws + 167 * MB + 786432); // 256KB
  float*          sxg    = (float*)(ws + 168 * MB);          // 32KB [4][2048]
  float*          accb   = (float*)(ws + 168 * MB + 32768);  // 32KB [4][2048]
  float*          outpre = (float*)(ws + 168 * MB + 65536);  // 16KB [4][1024]

  cvt_all_k<<<12800, 256, 0, stream>>>(x, xb, W_in, wbin, W_xp, wbxp, W_dt, wbdt);
  hipMemsetAsync(sxg, 0, 4 * DI * sizeof(float), stream);
  // xz = x @ W_in^T + b_in; cols<2048 -> xib bf16; cols>=2048 -> silu -> grm bf16
  gemm_bt<2><<<dim3(64, 32), 256, 0, stream>>>(xb, wbin, b_in, 4096, 1024, 1024, 1024,
                                               xib, grm, nullptr, nullptr, 2048);
  conv_k<<<16384, 256, 0, stream>>>(xib, conv_w, conv_b, xcb);
  sxg_k<<<dim3(2, 4, 64), 256, 0, stream>>>(xcb, grm, sxg);
  // xp = x_conv @ W_xp^T + b_xp -> xpb bf16 + bcI float2
  gemm_bt<0><<<dim3(64, 2), 256, 0, stream>>>(xcb, wbxp, b_xp, 192, 2048, 2048, 2048,
                                              xpb, bcI, nullptr, nullptr, 0);
  // dt path: softplus GEMM -> dtP u32 + dxgP u32x2 (LDS transpose epilogue)
  gemm_bt<1><<<dim3(64, 16), 256, 0, stream>>>(xpb, wbdt, b_dt, 2048, 64, XPW, 64,
                                               dtP, dxgP, xcb, grm, 0);
  scan_k<<<1024, 256, 0, stream>>>(dtP, dxgP, bcI, A_log, state0, accb, out + 4096);
  out_gemm_k<<<dim3(128, 4), 256, 0, stream>>>(accb, sxg, Dvec, W_out, b_out, outpre);
  ln_k<<<4, 256, 0, stream>>>(outpre, ln_g, ln_b, out);
}